// Round 1
// baseline (917.504 us; speedup 1.0000x reference)
//
#include <hip/hip_runtime.h>
#include <math.h>

#define NEG_SLOPE 0.2f

// ---------------------------------------------------------------- CSR build
__global__ void deg_count_kernel(const int* __restrict__ dst, int* __restrict__ deg, int E){
  int e = blockIdx.x * blockDim.x + threadIdx.x;
  if (e < E) atomicAdd(&deg[dst[e]], 1);
}

// single-block exclusive scan (in-place), a[n] = total. 1024 threads, 4 elems/thread/iter.
__global__ __launch_bounds__(1024) void scan_excl_kernel(int* a, int n){
  __shared__ int buf[1024];
  __shared__ int carry;
  int tid = threadIdx.x;
  if (tid == 0) carry = 0;
  __syncthreads();
  for (int base = 0; base < n; base += 4096){
    int idx = base + tid * 4;
    int4 v = {0,0,0,0};
    if (idx + 3 < n) v = *(const int4*)(a + idx);
    else {
      if (idx     < n) v.x = a[idx];
      if (idx + 1 < n) v.y = a[idx+1];
      if (idx + 2 < n) v.z = a[idx+2];
      if (idx + 3 < n) v.w = a[idx+3];
    }
    int s = v.x + v.y + v.z + v.w;
    buf[tid] = s; __syncthreads();
    int val = s;
    for (int off = 1; off < 1024; off <<= 1){
      int t = (tid >= off) ? buf[tid - off] : 0;
      __syncthreads();
      val += t;
      buf[tid] = val;
      __syncthreads();
    }
    int excl = val - s + carry;      // carry read by all threads here
    int o0 = excl, o1 = o0 + v.x, o2 = o1 + v.y, o3 = o2 + v.z;
    if (idx     < n) a[idx]   = o0;
    if (idx + 1 < n) a[idx+1] = o1;
    if (idx + 2 < n) a[idx+2] = o2;
    if (idx + 3 < n) a[idx+3] = o3;
    __syncthreads();                 // all reads of carry done
    if (tid == 1023) carry = excl + s;
    __syncthreads();
  }
  if (tid == 0) a[n] = carry;
}

__global__ void fill_kernel(const int* __restrict__ ei, const float* __restrict__ ea,
                            const int* __restrict__ csr_off, int* __restrict__ pos,
                            int* __restrict__ csr_src, float* __restrict__ csr_ea, int E){
  int e = blockIdx.x * blockDim.x + threadIdx.x;
  if (e >= E) return;
  int s = ei[e], d = ei[E + e];
  int p = atomicAdd(&pos[d], 1);
  int slot = csr_off[d] + p;
  csr_src[slot] = s;
  csr_ea[slot]  = ea[e];
}

// ---------------------------------------------------------------- GEMM: Y[N][M] = X[N][K] @ W[K][M] + bias
template<int M>
__global__ __launch_bounds__(256) void gemm_bias_kernel(
    const float* __restrict__ X, const float* __restrict__ W,
    const float* __restrict__ bias, float* __restrict__ Y, int N, int K)
{
  constexpr int CG  = M / 4;      // col groups (4 cols each)
  constexpr int RG  = 256 / CG;   // row groups
  constexpr int RPT = 64 / RG;    // rows per thread (row tile = 64)
  __shared__ float xs[64][17];    // +1 pad breaks bank conflicts
  __shared__ float ws[16][M];
  int tid = threadIdx.x;
  int r0  = blockIdx.x * 64;
  int cg  = tid % CG, rg = tid / CG;
  int col = cg * 4;
  float acc[RPT][4];
  #pragma unroll
  for (int i = 0; i < RPT; i++){ acc[i][0]=0.f; acc[i][1]=0.f; acc[i][2]=0.f; acc[i][3]=0.f; }

  for (int k0 = 0; k0 < K; k0 += 16){
    { // stage x tile: 64 rows x 16 k
      int row  = tid >> 2;
      int kb   = (tid & 3) * 4;
      int grow = r0 + row;
      #pragma unroll
      for (int j = 0; j < 4; j++){
        int k = k0 + kb + j;
        xs[row][kb + j] = (grow < N && k < K) ? X[(long)grow * K + k] : 0.f;
      }
    }
    { // stage W tile: 16 k x M cols
      constexpr int EPT = M / 16;
      int lin = tid * EPT;
      int kk  = lin / M;
      int c   = lin % M;
      int k   = k0 + kk;
      #pragma unroll
      for (int j = 0; j < EPT; j++)
        ws[kk][c + j] = (k < K) ? W[(long)k * M + c + j] : 0.f;
    }
    __syncthreads();
    #pragma unroll
    for (int kk = 0; kk < 16; kk++){
      float4 wv = *(const float4*)&ws[kk][col];
      #pragma unroll
      for (int i = 0; i < RPT; i++){
        float a = xs[rg * RPT + i][kk];
        acc[i][0] += a * wv.x; acc[i][1] += a * wv.y;
        acc[i][2] += a * wv.z; acc[i][3] += a * wv.w;
      }
    }
    __syncthreads();
  }
  float b0 = bias[col], b1 = bias[col+1], b2 = bias[col+2], b3 = bias[col+3];
  #pragma unroll
  for (int i = 0; i < RPT; i++){
    int row = r0 + rg * RPT + i;
    if (row < N){
      float4 o = make_float4(acc[i][0]+b0, acc[i][1]+b1, acc[i][2]+b2, acc[i][3]+b3);
      *(float4*)&Y[(long)row * M + col] = o;
    }
  }
}

// ---------------------------------------------------------------- fused edge softmax + aggregation
// one wave per dst node, online softmax over incoming edges
template<int HC>
__global__ __launch_bounds__(256) void agg_kernel(
    const float* __restrict__ xl, const float* __restrict__ xr,
    const int* __restrict__ csr_off, const int* __restrict__ csr_src,
    const float* __restrict__ csr_ea,
    const float* __restrict__ We, const float* __restrict__ att,
    const float* __restrict__ bias, float* __restrict__ hout,
    int N, int do_elu)
{
  constexpr int PL = HC / 64;                 // channels per lane (2 or 1)
  int lane = threadIdx.x & 63;
  int n = (blockIdx.x * blockDim.x + threadIdx.x) >> 6;
  if (n >= N) return;
  int c0 = lane * PL;
  float attv[PL], wev[PL], xrv[PL], acc[PL];
  #pragma unroll
  for (int k = 0; k < PL; k++){
    attv[k] = att[c0 + k];
    wev[k]  = We[c0 + k];
    xrv[k]  = xr[(long)n * HC + c0 + k];
    acc[k]  = 0.f;
  }
  int s = csr_off[n], e = csr_off[n + 1];
  float mrun = -INFINITY, lrun = 0.f;
  for (; s < e; ++s){
    int   srcn = csr_src[s];
    float eav  = csr_ea[s];
    float xlv[PL];
    if constexpr (PL == 2){
      float2 v = *(const float2*)(xl + (long)srcn * HC + c0);
      xlv[0] = v.x; xlv[1] = v.y;
    } else {
      xlv[0] = xl[(long)srcn * HC + c0];
    }
    float p = 0.f;
    #pragma unroll
    for (int k = 0; k < PL; k++){
      float t = xlv[k] + xrv[k] + eav * wev[k];
      float m = t > 0.f ? t : NEG_SLOPE * t;
      p += m * attv[k];
    }
    // reduce over the 8 lanes of this head (C=16: 8 lanes x 2ch, C=8: 8 lanes x 1ch)
    p += __shfl_xor(p, 1);
    p += __shfl_xor(p, 2);
    p += __shfl_xor(p, 4);
    float newm = fmaxf(mrun, p);
    float sc = __expf(mrun - newm);   // first edge: exp(-inf) = 0
    float pe = __expf(p - newm);
    lrun = lrun * sc + pe;
    #pragma unroll
    for (int k = 0; k < PL; k++) acc[k] = acc[k] * sc + pe * xlv[k];
    mrun = newm;
  }
  float inv = 1.f / (lrun + 1e-16f);
  #pragma unroll
  for (int k = 0; k < PL; k++){
    float o = acc[k] * inv + bias[c0 + k];
    if (do_elu) o = o > 0.f ? o : (__expf(o) - 1.f);
    hout[(long)n * HC + c0 + k] = o;
  }
}

// ---------------------------------------------------------------- final linear 64 -> 1, one wave per node
__global__ __launch_bounds__(256) void final_linear_kernel(
    const float* __restrict__ h, const float* __restrict__ Wlin,
    const float* __restrict__ blin, float* __restrict__ out, int N)
{
  int lane = threadIdx.x & 63;
  int n = (blockIdx.x * blockDim.x + threadIdx.x) >> 6;
  if (n >= N) return;
  float v = h[(long)n * 64 + lane] * Wlin[lane];
  #pragma unroll
  for (int off = 1; off < 64; off <<= 1) v += __shfl_xor(v, off);
  if (lane == 0) out[n] = v + blin[0];
}

// ----------------------------------------------------------------
extern "C" void kernel_launch(void* const* d_in, const int* in_sizes, int n_in,
                              void* d_out, int out_size, void* d_ws, size_t ws_size,
                              hipStream_t stream)
{
  const float* x  = (const float*)d_in[0];
  const float* ea = (const float*)d_in[1];
  const int*   ei = (const int*)d_in[2];
  const int N = in_sizes[0] / 15;
  const int E = in_sizes[1];

  const float* P[28];
  for (int i = 0; i < 28; i++) P[i] = (const float*)d_in[3 + i];
  const float* Wlin = (const float*)d_in[31];
  const float* blin = (const float*)d_in[32];

  // workspace carve, 256B aligned blocks
  size_t off = 0;
  auto carve = [&](size_t bytes) -> char* {
    char* p = (char*)d_ws + off;
    off = (off + bytes + 255) & ~(size_t)255;
    return p;
  };
  int*   csr_off = (int*)  carve(sizeof(int)   * (size_t)(N + 1));
  int*   pos     = (int*)  carve(sizeof(int)   * (size_t)N);
  int*   csr_src = (int*)  carve(sizeof(int)   * (size_t)E);
  float* csr_ea  = (float*)carve(sizeof(float) * (size_t)E);
  float* xl      = (float*)carve(sizeof(float) * (size_t)N * 128);
  float* xr      = (float*)carve(sizeof(float) * (size_t)N * 128);
  float* hA      = (float*)carve(sizeof(float) * (size_t)N * 128);
  float* hB      = (float*)carve(sizeof(float) * (size_t)N * 128);

  hipMemsetAsync(csr_off, 0, sizeof(int) * (size_t)(N + 1), stream);
  hipMemsetAsync(pos,     0, sizeof(int) * (size_t)N,       stream);

  int eb = (E + 255) / 256;
  deg_count_kernel<<<eb, 256, 0, stream>>>(ei + E, csr_off, E);
  scan_excl_kernel<<<1, 1024, 0, stream>>>(csr_off, N);
  fill_kernel<<<eb, 256, 0, stream>>>(ei, ea, csr_off, pos, csr_src, csr_ea, E);

  int gb = (N + 63) / 64;   // gemm grid (64-row tiles)
  int ab = (N + 3) / 4;     // agg/final grid (4 waves per block)

  // layer 1: din=15, H*C=128, ELU
  gemm_bias_kernel<128><<<gb, 256, 0, stream>>>(x, P[0], P[1], xl, N, 15);
  gemm_bias_kernel<128><<<gb, 256, 0, stream>>>(x, P[2], P[3], xr, N, 15);
  agg_kernel<128><<<ab, 256, 0, stream>>>(xl, xr, csr_off, csr_src, csr_ea, P[4], P[5], P[6], hA, N, 1);
  // layer 2: din=128, ELU
  gemm_bias_kernel<128><<<gb, 256, 0, stream>>>(hA, P[7],  P[8],  xl, N, 128);
  gemm_bias_kernel<128><<<gb, 256, 0, stream>>>(hA, P[9],  P[10], xr, N, 128);
  agg_kernel<128><<<ab, 256, 0, stream>>>(xl, xr, csr_off, csr_src, csr_ea, P[11], P[12], P[13], hB, N, 1);
  // layer 3: din=128, ELU
  gemm_bias_kernel<128><<<gb, 256, 0, stream>>>(hB, P[14], P[15], xl, N, 128);
  gemm_bias_kernel<128><<<gb, 256, 0, stream>>>(hB, P[16], P[17], xr, N, 128);
  agg_kernel<128><<<ab, 256, 0, stream>>>(xl, xr, csr_off, csr_src, csr_ea, P[18], P[19], P[20], hA, N, 1);
  // layer 4: din=128, H*C=64, no ELU
  gemm_bias_kernel<64><<<gb, 256, 0, stream>>>(hA, P[21], P[22], xl, N, 128);
  gemm_bias_kernel<64><<<gb, 256, 0, stream>>>(hA, P[23], P[24], xr, N, 128);
  agg_kernel<64><<<ab, 256, 0, stream>>>(xl, xr, csr_off, csr_src, csr_ea, P[25], P[26], P[27], hB, N, 0);
  // final linear 64 -> 1
  final_linear_kernel<<<ab, 256, 0, stream>>>(hB, Wlin, blin, (float*)d_out, N);
}

// Round 2
// 722.290 us; speedup vs baseline: 1.2703x; 1.2703x over previous
//
#include <hip/hip_runtime.h>
#include <math.h>

#define NEG_SLOPE 0.2f

// ---------------------------------------------------------------- CSR build
__global__ void deg_count_kernel(const int* __restrict__ dst, int* __restrict__ deg, int E){
  int e = blockIdx.x * blockDim.x + threadIdx.x;
  if (e < E) atomicAdd(&deg[dst[e]], 1);
}

// single-block exclusive scan (in-place), a[n] = total. 1024 threads, 4 elems/thread/iter.
__global__ __launch_bounds__(1024) void scan_excl_kernel(int* a, int n){
  __shared__ int buf[1024];
  __shared__ int carry;
  int tid = threadIdx.x;
  if (tid == 0) carry = 0;
  __syncthreads();
  for (int base = 0; base < n; base += 4096){
    int idx = base + tid * 4;
    int4 v = {0,0,0,0};
    if (idx + 3 < n) v = *(const int4*)(a + idx);
    else {
      if (idx     < n) v.x = a[idx];
      if (idx + 1 < n) v.y = a[idx+1];
      if (idx + 2 < n) v.z = a[idx+2];
      if (idx + 3 < n) v.w = a[idx+3];
    }
    int s = v.x + v.y + v.z + v.w;
    buf[tid] = s; __syncthreads();
    int val = s;
    for (int off = 1; off < 1024; off <<= 1){
      int t = (tid >= off) ? buf[tid - off] : 0;
      __syncthreads();
      val += t;
      buf[tid] = val;
      __syncthreads();
    }
    int excl = val - s + carry;      // carry read by all threads here
    int o0 = excl, o1 = o0 + v.x, o2 = o1 + v.y, o3 = o2 + v.z;
    if (idx     < n) a[idx]   = o0;
    if (idx + 1 < n) a[idx+1] = o1;
    if (idx + 2 < n) a[idx+2] = o2;
    if (idx + 3 < n) a[idx+3] = o3;
    __syncthreads();                 // all reads of carry done
    if (tid == 1023) carry = excl + s;
    __syncthreads();
  }
  if (tid == 0) a[n] = carry;
}

// pack (src, edge_attr) per CSR slot into one int2
__global__ void fill_kernel(const int* __restrict__ ei, const float* __restrict__ ea,
                            const int* __restrict__ csr_off, int* __restrict__ pos,
                            int2* __restrict__ csr_pack, int E){
  int e = blockIdx.x * blockDim.x + threadIdx.x;
  if (e >= E) return;
  int s = ei[e], d = ei[E + e];
  int p = atomicAdd(&pos[d], 1);
  int slot = csr_off[d] + p;
  csr_pack[slot] = make_int2(s, __float_as_int(ea[e]));
}

// ---------------------------------------------------------------- fused dual GEMM:
// Y1 = X@W1 + b1, Y2 = X@W2 + b2 ; shares the LDS x-tile between both products
template<int M>
__global__ __launch_bounds__(256) void gemm2_bias_kernel(
    const float* __restrict__ X,
    const float* __restrict__ W1, const float* __restrict__ b1,
    const float* __restrict__ W2, const float* __restrict__ b2,
    float* __restrict__ Y1, float* __restrict__ Y2, int N, int K)
{
  constexpr int CG  = M / 4;      // col groups (4 cols each)
  constexpr int RG  = 256 / CG;   // row groups
  constexpr int RPT = 64 / RG;    // rows per thread (row tile = 64)
  __shared__ float xs[64][17];    // +1 pad breaks bank conflicts
  __shared__ float ws1[16][M];
  __shared__ float ws2[16][M];
  int tid = threadIdx.x;
  int r0  = blockIdx.x * 64;
  int cg  = tid % CG, rg = tid / CG;
  int col = cg * 4;
  float acc1[RPT][4], acc2[RPT][4];
  #pragma unroll
  for (int i = 0; i < RPT; i++)
    #pragma unroll
    for (int j = 0; j < 4; j++){ acc1[i][j] = 0.f; acc2[i][j] = 0.f; }

  for (int k0 = 0; k0 < K; k0 += 16){
    { // stage x tile: 64 rows x 16 k
      int row  = tid >> 2;
      int kb   = (tid & 3) * 4;
      int grow = r0 + row;
      #pragma unroll
      for (int j = 0; j < 4; j++){
        int k = k0 + kb + j;
        xs[row][kb + j] = (grow < N && k < K) ? X[(long)grow * K + k] : 0.f;
      }
    }
    { // stage W tiles: 16 k x M cols, both weights
      constexpr int EPT = M / 16;
      int lin = tid * EPT;
      int kk  = lin / M;
      int c   = lin % M;
      int k   = k0 + kk;
      #pragma unroll
      for (int j = 0; j < EPT; j++){
        ws1[kk][c + j] = (k < K) ? W1[(long)k * M + c + j] : 0.f;
        ws2[kk][c + j] = (k < K) ? W2[(long)k * M + c + j] : 0.f;
      }
    }
    __syncthreads();
    #pragma unroll
    for (int kk = 0; kk < 16; kk++){
      float4 w1 = *(const float4*)&ws1[kk][col];
      float4 w2 = *(const float4*)&ws2[kk][col];
      #pragma unroll
      for (int i = 0; i < RPT; i++){
        float a = xs[rg * RPT + i][kk];
        acc1[i][0] += a * w1.x; acc1[i][1] += a * w1.y;
        acc1[i][2] += a * w1.z; acc1[i][3] += a * w1.w;
        acc2[i][0] += a * w2.x; acc2[i][1] += a * w2.y;
        acc2[i][2] += a * w2.z; acc2[i][3] += a * w2.w;
      }
    }
    __syncthreads();
  }
  float4 bv1 = *(const float4*)&b1[col];
  float4 bv2 = *(const float4*)&b2[col];
  #pragma unroll
  for (int i = 0; i < RPT; i++){
    int row = r0 + rg * RPT + i;
    if (row < N){
      float4 o1 = make_float4(acc1[i][0]+bv1.x, acc1[i][1]+bv1.y, acc1[i][2]+bv1.z, acc1[i][3]+bv1.w);
      float4 o2 = make_float4(acc2[i][0]+bv2.x, acc2[i][1]+bv2.y, acc2[i][2]+bv2.z, acc2[i][3]+bv2.w);
      *(float4*)&Y1[(long)row * M + col] = o1;
      *(float4*)&Y2[(long)row * M + col] = o2;
    }
  }
}

// ---------------------------------------------------------------- fused edge softmax + aggregation
// one wave per dst node, online softmax, edge loop batched by 4 for MLP/ILP
template<int HC>
__global__ __launch_bounds__(256) void agg_kernel(
    const float* __restrict__ xl, const float* __restrict__ xr,
    const int* __restrict__ csr_off, const int2* __restrict__ csr_pack,
    const float* __restrict__ We, const float* __restrict__ att,
    const float* __restrict__ bias, float* __restrict__ hout,
    int N, int do_elu)
{
  constexpr int PL = HC / 64;                 // channels per lane (2 or 1)
  int lane = threadIdx.x & 63;
  int n = (blockIdx.x * blockDim.x + threadIdx.x) >> 6;
  if (n >= N) return;
  int c0 = lane * PL;
  float attv[PL], wev[PL], xrv[PL], acc[PL];
  #pragma unroll
  for (int k = 0; k < PL; k++){
    attv[k] = att[c0 + k];
    wev[k]  = We[c0 + k];
    xrv[k]  = xr[(long)n * HC + c0 + k];
    acc[k]  = 0.f;
  }
  int s = csr_off[n], e = csr_off[n + 1];
  float mrun = -INFINITY, lrun = 0.f;
  for (; s < e; s += 4){
    // gather 4 edges' (src, ea) and xl rows; tail slots clamped, masked later
    int   srcj[4]; float eaj[4];
    #pragma unroll
    for (int j = 0; j < 4; j++){
      int idx = (s + j < e) ? s + j : e - 1;
      int2 pk = csr_pack[idx];
      srcj[j] = pk.x;
      eaj[j]  = __int_as_float(pk.y);
    }
    float xlv[4][PL];
    #pragma unroll
    for (int j = 0; j < 4; j++){
      const float* row = xl + (long)srcj[j] * HC + c0;
      if constexpr (PL == 2){
        float2 v = *(const float2*)row;
        xlv[j][0] = v.x; xlv[j][1] = v.y;
      } else {
        xlv[j][0] = row[0];
      }
    }
    float p[4];
    #pragma unroll
    for (int j = 0; j < 4; j++){
      float pp = 0.f;
      #pragma unroll
      for (int k = 0; k < PL; k++){
        float t = xlv[j][k] + xrv[k] + eaj[j] * wev[k];
        float m = t > 0.f ? t : NEG_SLOPE * t;
        pp += m * attv[k];
      }
      p[j] = pp;
    }
    // per-head reduce over 8 lanes; 4 independent depth-3 chains
    #pragma unroll
    for (int j = 0; j < 4; j++){
      p[j] += __shfl_xor(p[j], 1);
      p[j] += __shfl_xor(p[j], 2);
      p[j] += __shfl_xor(p[j], 4);
      if (s + j >= e) p[j] = -INFINITY;   // mask tail
    }
    float bm   = fmaxf(fmaxf(p[0], p[1]), fmaxf(p[2], p[3]));
    float newm = fmaxf(mrun, bm);
    float sc   = __expf(mrun - newm);     // first batch: exp(-inf) = 0
    float pe[4];
    #pragma unroll
    for (int j = 0; j < 4; j++) pe[j] = __expf(p[j] - newm);
    lrun = lrun * sc + (pe[0] + pe[1]) + (pe[2] + pe[3]);
    #pragma unroll
    for (int k = 0; k < PL; k++){
      float a = acc[k] * sc;
      a += pe[0] * xlv[0][k];
      a += pe[1] * xlv[1][k];
      a += pe[2] * xlv[2][k];
      a += pe[3] * xlv[3][k];
      acc[k] = a;
    }
    mrun = newm;
  }
  float inv = 1.f / (lrun + 1e-16f);
  #pragma unroll
  for (int k = 0; k < PL; k++){
    float o = acc[k] * inv + bias[c0 + k];
    if (do_elu) o = o > 0.f ? o : (__expf(o) - 1.f);
    hout[(long)n * HC + c0 + k] = o;
  }
}

// ---------------------------------------------------------------- final linear 64 -> 1, one wave per node
__global__ __launch_bounds__(256) void final_linear_kernel(
    const float* __restrict__ h, const float* __restrict__ Wlin,
    const float* __restrict__ blin, float* __restrict__ out, int N)
{
  int lane = threadIdx.x & 63;
  int n = (blockIdx.x * blockDim.x + threadIdx.x) >> 6;
  if (n >= N) return;
  float v = h[(long)n * 64 + lane] * Wlin[lane];
  #pragma unroll
  for (int off = 1; off < 64; off <<= 1) v += __shfl_xor(v, off);
  if (lane == 0) out[n] = v + blin[0];
}

// ----------------------------------------------------------------
extern "C" void kernel_launch(void* const* d_in, const int* in_sizes, int n_in,
                              void* d_out, int out_size, void* d_ws, size_t ws_size,
                              hipStream_t stream)
{
  const float* x  = (const float*)d_in[0];
  const float* ea = (const float*)d_in[1];
  const int*   ei = (const int*)d_in[2];
  const int N = in_sizes[0] / 15;
  const int E = in_sizes[1];

  const float* P[28];
  for (int i = 0; i < 28; i++) P[i] = (const float*)d_in[3 + i];
  const float* Wlin = (const float*)d_in[31];
  const float* blin = (const float*)d_in[32];

  // workspace carve, 256B aligned blocks
  size_t off = 0;
  auto carve = [&](size_t bytes) -> char* {
    char* p = (char*)d_ws + off;
    off = (off + bytes + 255) & ~(size_t)255;
    return p;
  };
  int*   csr_off  = (int*)  carve(sizeof(int)  * (size_t)(N + 1));
  int*   pos      = (int*)  carve(sizeof(int)  * (size_t)N);
  int2*  csr_pack = (int2*) carve(sizeof(int2) * (size_t)E);
  float* xl       = (float*)carve(sizeof(float) * (size_t)N * 128);
  float* xr       = (float*)carve(sizeof(float) * (size_t)N * 128);
  float* hA       = (float*)carve(sizeof(float) * (size_t)N * 128);
  float* hB       = (float*)carve(sizeof(float) * (size_t)N * 128);

  hipMemsetAsync(csr_off, 0, sizeof(int) * (size_t)(N + 1), stream);
  hipMemsetAsync(pos,     0, sizeof(int) * (size_t)N,       stream);

  int eb = (E + 255) / 256;
  deg_count_kernel<<<eb, 256, 0, stream>>>(ei + E, csr_off, E);
  scan_excl_kernel<<<1, 1024, 0, stream>>>(csr_off, N);
  fill_kernel<<<eb, 256, 0, stream>>>(ei, ea, csr_off, pos, csr_pack, E);

  int gb = (N + 63) / 64;   // gemm grid (64-row tiles)
  int ab = (N + 3) / 4;     // agg/final grid (4 waves per block)

  // layer 1: din=15, H*C=128, ELU
  gemm2_bias_kernel<128><<<gb, 256, 0, stream>>>(x, P[0], P[1], P[2], P[3], xl, xr, N, 15);
  agg_kernel<128><<<ab, 256, 0, stream>>>(xl, xr, csr_off, csr_pack, P[4], P[5], P[6], hA, N, 1);
  // layer 2: din=128, ELU
  gemm2_bias_kernel<128><<<gb, 256, 0, stream>>>(hA, P[7], P[8], P[9], P[10], xl, xr, N, 128);
  agg_kernel<128><<<ab, 256, 0, stream>>>(xl, xr, csr_off, csr_pack, P[11], P[12], P[13], hB, N, 1);
  // layer 3: din=128, ELU
  gemm2_bias_kernel<128><<<gb, 256, 0, stream>>>(hB, P[14], P[15], P[16], P[17], xl, xr, N, 128);
  agg_kernel<128><<<ab, 256, 0, stream>>>(xl, xr, csr_off, csr_pack, P[18], P[19], P[20], hA, N, 1);
  // layer 4: din=128, H*C=64, no ELU
  gemm2_bias_kernel<64><<<gb, 256, 0, stream>>>(hA, P[21], P[22], P[23], P[24], xl, xr, N, 128);
  agg_kernel<64><<<ab, 256, 0, stream>>>(xl, xr, csr_off, csr_pack, P[25], P[26], P[27], hB, N, 0);
  // final linear 64 -> 1
  final_linear_kernel<<<ab, 256, 0, stream>>>(hB, Wlin, blin, (float*)d_out, N);
}

// Round 3
// 641.105 us; speedup vs baseline: 1.4311x; 1.1266x over previous
//
#include <hip/hip_runtime.h>
#include <math.h>

#define NEG_SLOPE 0.2f

// ---------------------------------------------------------------- CSR build
__global__ void deg_count_kernel(const int* __restrict__ dst, int* __restrict__ deg, int E){
  int e = blockIdx.x * blockDim.x + threadIdx.x;
  if (e < E) atomicAdd(&deg[dst[e]], 1);
}

// segment-base allocation: order across nodes is arbitrary, CSR doesn't care
__global__ void base_assign_kernel(const int* __restrict__ deg, int* __restrict__ base,
                                   int* __restrict__ counter, int N){
  int n = blockIdx.x * blockDim.x + threadIdx.x;
  if (n < N) base[n] = atomicAdd(counter, deg[n]);
}

// pack (src, edge_attr) per CSR slot into one int2
__global__ void fill_kernel(const int* __restrict__ ei, const float* __restrict__ ea,
                            const int* __restrict__ base, int* __restrict__ pos,
                            int2* __restrict__ csr_pack, int E){
  int e = blockIdx.x * blockDim.x + threadIdx.x;
  if (e >= E) return;
  int s = ei[e], d = ei[E + e];
  int p = atomicAdd(&pos[d], 1);
  csr_pack[base[d] + p] = make_int2(s, __float_as_int(ea[e]));
}

// ---------------------------------------------------------------- GEMM tile kernel
// blockIdx.y selects (W1,b1,Y1) or (W2,b2,Y2). Whole X row-tile staged once in LDS,
// W staged in 16-k slabs. Per thread: 4 rows x 4 cols.
template<int M, int K>
__global__ __launch_bounds__(256) void gemm_tile_kernel(
    const float* __restrict__ X,
    const float* __restrict__ W1, const float* __restrict__ b1,
    const float* __restrict__ W2, const float* __restrict__ b2,
    float* __restrict__ Y1, float* __restrict__ Y2, int N)
{
  constexpr int CG   = M / 4;            // col groups (4 cols each): 32 or 16
  constexpr int RG   = 256 / CG;         // row groups: 8 or 16
  constexpr int ROWS = 4 * RG;           // 32 or 64
  constexpr int KP   = (K == 15) ? 16 : K;
  __shared__ float xs[ROWS * KP];
  __shared__ float ws[16 * M];

  const float* W  = blockIdx.y ? W2 : W1;
  const float* bs = blockIdx.y ? b2 : b1;
  float*       Y  = blockIdx.y ? Y2 : Y1;

  int tid = threadIdx.x;
  int r0  = blockIdx.x * ROWS;
  int cg  = tid % CG, rg = tid / CG;
  int col = cg * 4;

  // stage whole X tile (ROWS x KP), float4 chunks, consecutive lanes -> consecutive 16B
  constexpr int XCH = ROWS * KP / 4;
  for (int q = tid; q < XCH; q += 256){
    int r  = (4 * q) / KP;
    int kp = (4 * q) % KP;
    int grow = r0 + r;
    float4 v = {0.f, 0.f, 0.f, 0.f};
    if (grow < N){
      if constexpr (K == KP){
        v = *(const float4*)(X + (long)grow * K + kp);
      } else {
        const float* px = X + (long)grow * K;
        if (kp + 0 < K) v.x = px[kp + 0];
        if (kp + 1 < K) v.y = px[kp + 1];
        if (kp + 2 < K) v.z = px[kp + 2];
        if (kp + 3 < K) v.w = px[kp + 3];
      }
    }
    *(float4*)&xs[r * KP + kp] = v;
  }

  float acc[4][4];
  #pragma unroll
  for (int i = 0; i < 4; i++)
    #pragma unroll
    for (int j = 0; j < 4; j++) acc[i][j] = 0.f;

  for (int k0 = 0; k0 < KP; k0 += 16){
    __syncthreads();               // ws write-after-read from previous slab
    constexpr int WCH = 16 * M / 4;
    for (int q = tid; q < WCH; q += 256){
      int kk = (4 * q) / M;
      int c  = (4 * q) % M;
      int k  = k0 + kk;
      float4 v = {0.f, 0.f, 0.f, 0.f};
      if (k < K) v = *(const float4*)(W + (long)k * M + c);
      *(float4*)&ws[kk * M + c] = v;
    }
    __syncthreads();               // xs (first iter) + ws visible
    #pragma unroll
    for (int kb = 0; kb < 16; kb += 4){
      float4 xv[4];
      #pragma unroll
      for (int i = 0; i < 4; i++)
        xv[i] = *(const float4*)&xs[(rg * 4 + i) * KP + k0 + kb];
      #pragma unroll
      for (int t = 0; t < 4; t++){
        float4 wv = *(const float4*)&ws[(kb + t) * M + col];
        #pragma unroll
        for (int i = 0; i < 4; i++){
          float a = (t == 0) ? xv[i].x : (t == 1) ? xv[i].y : (t == 2) ? xv[i].z : xv[i].w;
          acc[i][0] += a * wv.x; acc[i][1] += a * wv.y;
          acc[i][2] += a * wv.z; acc[i][3] += a * wv.w;
        }
      }
    }
  }

  float4 bv = *(const float4*)&bs[col];
  #pragma unroll
  for (int i = 0; i < 4; i++){
    int row = r0 + rg * 4 + i;
    if (row < N){
      float4 o = make_float4(acc[i][0] + bv.x, acc[i][1] + bv.y,
                             acc[i][2] + bv.z, acc[i][3] + bv.w);
      *(float4*)&Y[(long)row * M + col] = o;
    }
  }
}

// ---------------------------------------------------------------- fused edge softmax + aggregation
// one wave per dst node, online softmax, edge loop batched by 8 for MLP/ILP
template<int HC>
__global__ __launch_bounds__(256) void agg_kernel(
    const float* __restrict__ xl, const float* __restrict__ xr,
    const int* __restrict__ base, const int* __restrict__ deg,
    const int2* __restrict__ csr_pack,
    const float* __restrict__ We, const float* __restrict__ att,
    const float* __restrict__ bias, float* __restrict__ hout,
    int N, int do_elu)
{
  constexpr int PL = HC / 64;                 // channels per lane (2 or 1)
  int lane = threadIdx.x & 63;
  int n = (blockIdx.x * blockDim.x + threadIdx.x) >> 6;
  if (n >= N) return;
  int c0 = lane * PL;
  float attv[PL], wev[PL], xrv[PL], acc[PL];
  #pragma unroll
  for (int k = 0; k < PL; k++){
    attv[k] = att[c0 + k];
    wev[k]  = We[c0 + k];
    xrv[k]  = xr[(long)n * HC + c0 + k];
    acc[k]  = 0.f;
  }
  int s0 = base[n], e = s0 + deg[n];
  float mrun = -INFINITY, lrun = 0.f;
  for (int s = s0; s < e; s += 8){
    int   srcj[8]; float eaj[8];
    #pragma unroll
    for (int j = 0; j < 8; j++){
      int idx = (s + j < e) ? s + j : e - 1;   // clamp tail (masked below)
      int2 pk = csr_pack[idx];
      srcj[j] = pk.x;
      eaj[j]  = __int_as_float(pk.y);
    }
    float xlv[8][PL];
    #pragma unroll
    for (int j = 0; j < 8; j++){
      const float* row = xl + (long)srcj[j] * HC + c0;
      if constexpr (PL == 2){
        float2 v = *(const float2*)row;
        xlv[j][0] = v.x; xlv[j][1] = v.y;
      } else {
        xlv[j][0] = row[0];
      }
    }
    float p[8];
    #pragma unroll
    for (int j = 0; j < 8; j++){
      float pp = 0.f;
      #pragma unroll
      for (int k = 0; k < PL; k++){
        float t = xlv[j][k] + xrv[k] + eaj[j] * wev[k];
        float m = t > 0.f ? t : NEG_SLOPE * t;
        pp += m * attv[k];
      }
      p[j] = pp;
    }
    // per-head reduce over 8 lanes; 8 independent depth-3 chains
    #pragma unroll
    for (int j = 0; j < 8; j++){
      p[j] += __shfl_xor(p[j], 1);
      p[j] += __shfl_xor(p[j], 2);
      p[j] += __shfl_xor(p[j], 4);
      if (s + j >= e) p[j] = -INFINITY;   // mask tail
    }
    float m01 = fmaxf(p[0], p[1]), m23 = fmaxf(p[2], p[3]);
    float m45 = fmaxf(p[4], p[5]), m67 = fmaxf(p[6], p[7]);
    float bm  = fmaxf(fmaxf(m01, m23), fmaxf(m45, m67));
    float newm = fmaxf(mrun, bm);
    float sc   = __expf(mrun - newm);     // first batch: exp(-inf) = 0
    float pe[8];
    #pragma unroll
    for (int j = 0; j < 8; j++) pe[j] = __expf(p[j] - newm);
    lrun = lrun * sc + ((pe[0] + pe[1]) + (pe[2] + pe[3]))
                     + ((pe[4] + pe[5]) + (pe[6] + pe[7]));
    #pragma unroll
    for (int k = 0; k < PL; k++){
      float a = acc[k] * sc;
      #pragma unroll
      for (int j = 0; j < 8; j++) a += pe[j] * xlv[j][k];
      acc[k] = a;
    }
    mrun = newm;
  }
  float inv = 1.f / (lrun + 1e-16f);
  #pragma unroll
  for (int k = 0; k < PL; k++){
    float o = acc[k] * inv + bias[c0 + k];
    if (do_elu) o = o > 0.f ? o : (__expf(o) - 1.f);
    hout[(long)n * HC + c0 + k] = o;
  }
}

// ---------------------------------------------------------------- final linear 64 -> 1, one wave per node
__global__ __launch_bounds__(256) void final_linear_kernel(
    const float* __restrict__ h, const float* __restrict__ Wlin,
    const float* __restrict__ blin, float* __restrict__ out, int N)
{
  int lane = threadIdx.x & 63;
  int n = (blockIdx.x * blockDim.x + threadIdx.x) >> 6;
  if (n >= N) return;
  float v = h[(long)n * 64 + lane] * Wlin[lane];
  #pragma unroll
  for (int off = 1; off < 64; off <<= 1) v += __shfl_xor(v, off);
  if (lane == 0) out[n] = v + blin[0];
}

// ----------------------------------------------------------------
extern "C" void kernel_launch(void* const* d_in, const int* in_sizes, int n_in,
                              void* d_out, int out_size, void* d_ws, size_t ws_size,
                              hipStream_t stream)
{
  const float* x  = (const float*)d_in[0];
  const float* ea = (const float*)d_in[1];
  const int*   ei = (const int*)d_in[2];
  const int N = in_sizes[0] / 15;
  const int E = in_sizes[1];

  const float* P[28];
  for (int i = 0; i < 28; i++) P[i] = (const float*)d_in[3 + i];
  const float* Wlin = (const float*)d_in[31];
  const float* blin = (const float*)d_in[32];

  // workspace carve, 256B aligned blocks
  size_t off = 0;
  auto carve = [&](size_t bytes) -> char* {
    char* p = (char*)d_ws + off;
    off = (off + bytes + 255) & ~(size_t)255;
    return p;
  };
  int*   meta     = (int*)  carve(sizeof(int)  * (size_t)(3 * N + 64));
  int*   deg      = meta;                // [N]   zeroed
  int*   pos      = meta + N;            // [N]   zeroed
  int*   base     = meta + 2 * N;        // [N]
  int*   counter  = meta + 3 * N;        // [1]   zeroed
  int2*  csr_pack = (int2*) carve(sizeof(int2) * (size_t)E);
  float* xl       = (float*)carve(sizeof(float) * (size_t)N * 128);
  float* xr       = (float*)carve(sizeof(float) * (size_t)N * 128);
  float* hA       = (float*)carve(sizeof(float) * (size_t)N * 128);
  float* hB       = (float*)carve(sizeof(float) * (size_t)N * 128);

  hipMemsetAsync(deg,     0, sizeof(int) * (size_t)(2 * N), stream);   // deg+pos
  hipMemsetAsync(counter, 0, sizeof(int), stream);

  int eb = (E + 255) / 256;
  int nb = (N + 255) / 256;
  deg_count_kernel <<<eb, 256, 0, stream>>>(ei + E, deg, E);
  base_assign_kernel<<<nb, 256, 0, stream>>>(deg, base, counter, N);
  fill_kernel      <<<eb, 256, 0, stream>>>(ei, ea, base, pos, csr_pack, E);

  dim3 g128((N + 31) / 32, 2);   // M=128 tiles: 32 rows
  dim3 g64 ((N + 63) / 64, 2);   // M=64  tiles: 64 rows
  int ab = (N + 3) / 4;          // agg/final grid (4 waves per block)

  // layer 1: din=15, H*C=128, ELU
  gemm_tile_kernel<128, 15><<<g128, 256, 0, stream>>>(x, P[0], P[1], P[2], P[3], xl, xr, N);
  agg_kernel<128><<<ab, 256, 0, stream>>>(xl, xr, base, deg, csr_pack, P[4], P[5], P[6], hA, N, 1);
  // layer 2: din=128, ELU
  gemm_tile_kernel<128, 128><<<g128, 256, 0, stream>>>(hA, P[7], P[8], P[9], P[10], xl, xr, N);
  agg_kernel<128><<<ab, 256, 0, stream>>>(xl, xr, base, deg, csr_pack, P[11], P[12], P[13], hB, N, 1);
  // layer 3: din=128, ELU
  gemm_tile_kernel<128, 128><<<g128, 256, 0, stream>>>(hB, P[14], P[15], P[16], P[17], xl, xr, N);
  agg_kernel<128><<<ab, 256, 0, stream>>>(xl, xr, base, deg, csr_pack, P[18], P[19], P[20], hA, N, 1);
  // layer 4: din=128, H*C=64, no ELU
  gemm_tile_kernel<64, 128><<<g64, 256, 0, stream>>>(hA, P[21], P[22], P[23], P[24], xl, xr, N);
  agg_kernel<64><<<ab, 256, 0, stream>>>(xl, xr, base, deg, csr_pack, P[25], P[26], P[27], hB, N, 0);
  // final linear 64 -> 1
  final_linear_kernel<<<ab, 256, 0, stream>>>(hB, Wlin, blin, (float*)d_out, N);
}